// Round 16
// baseline (171.650 us; speedup 1.0000x reference)
//
#include <hip/hip_runtime.h>
#include <cfloat>
#include <cstddef>
#include <cstdint>

#define HW 9216
#define MROWS 2304
#define PARTS 7         // column-parts per (bb,row-group): 62|60 16-col groups each
#define NGRPC 432       // 6912/16 compressed groups (valid columns only)

typedef _Float16 half8 __attribute__((ext_vector_type(8)));
typedef float f32x4 __attribute__((ext_vector_type(4)));

// Compressed column space: only the 6912 non-hole columns, ascending original j.
//   k < 2304            -> j = k                       (rows 0..23)
//   2304 <= k < 4608    -> r = 24 + (k-2304)/48, c = (k-2304)%48,
//                          j = r*96 + (c < cb ? c : c+48)   (cb = 20 or 28 per branch)
//   k >= 4608           -> j = k + 2304                (rows 72..95)
// Mapping is strictly increasing -> compressed-index tie-break == original tie-break.
// bpack (B fragments, 16x16x32 layout): half8 index = (((dt*8+bb)*2 + c)*432 + g)*64 + lane
// apack (A fragments): half8 index = ((((bb*36+rg)*4 + rt)*2 + c)*2 + dt)*64 + lane
constexpr size_t OFF_BPB  = 0;                                 // 14,155,776 B
constexpr size_t OFF_APA  = OFF_BPB + 2ull*8*2*NGRPC*64*16;
constexpr size_t OFF_PVAL = OFF_APA + 8ull*36*4*2*2*64*16;     // +4,718,592
constexpr size_t OFF_PIDX = OFF_PVAL + 8ull*PARTS*MROWS*4;     // 516,096 each
constexpr size_t OFF_ORI  = OFF_PIDX + 8ull*PARTS*MROWS*4;
constexpr size_t OFF_CFO  = OFF_ORI  + 36864;
constexpr size_t OFF_CFF  = OFF_CFO  + 147456;
constexpr size_t OFF_SO   = OFF_CFF  + 147456;
constexpr size_t OFF_SF   = OFF_SO   + 1024;
constexpr size_t OFF_INVA = OFF_SF   + 1024;                   // 8*2304 f32

__device__ __forceinline__ int comp_to_orig(int k, int cb) {
    if (k < 2304) return k;
    if (k < 4608) {
        int k2 = k - 2304;
        int r = 24 + k2 / 48, c = k2 % 48;
        return r * 96 + (c < cb ? c : c + 48);
    }
    return k + 2304;
}

// K0: fused pack (bodies identical to the validated split kernels).
// grid (252, 8 bb), 256t.
//   blockIdx.x < 216 : B-side pack over compressed cols (k = x*32 + t&31, oct = t>>5)
//   blockIdx.x >= 216: A-side pack + inv norms + flag zeroing, rg = x-216
__global__ __launch_bounds__(256) void pack_kernel(
    const float* __restrict__ x, const float* __restrict__ flip,
    half8* __restrict__ bpB, half8* __restrict__ apA, float* __restrict__ invA,
    int* __restrict__ cfo, int* __restrict__ cff)
{
    __shared__ float nsq[8][32];
    __shared__ float ivs[32];
    __shared__ float red[4][64];
    int bb = blockIdx.y, b = bb >> 1, br = bb & 1;
    int t = threadIdx.x;
    if (blockIdx.x < 216) {
        // ---- B-side pack ----
        int col = t & 31, oct = t >> 5;
        int k = blockIdx.x * 32 + col;
        int cb = br ? 28 : 20;
        int j = comp_to_orig(k, cb);
        const float* Bm = br ? (flip + (size_t)b * 64 * HW)
                             : (x + (size_t)b * 128 * HW + (size_t)64 * HW);
        float v[8];
        float part = 0.f;
        #pragma unroll
        for (int e = 0; e < 8; ++e) {
            v[e] = Bm[(size_t)(oct * 8 + e) * HW + j];
            part += v[e] * v[e];
        }
        nsq[oct][col] = part;
        __syncthreads();
        if (oct == 0) {
            float tot = 0.f;
            #pragma unroll
            for (int o = 0; o < 8; ++o) tot += nsq[o][col];
            ivs[col] = 1.f / sqrtf(tot);
        }
        __syncthreads();
        float iv = ivs[col];
        half8 hv, lv;
        #pragma unroll
        for (int e = 0; e < 8; ++e) {
            float s = v[e] * iv;
            _Float16 h = (_Float16)s;
            hv[e] = h;
            lv[e] = (_Float16)(s - (float)h);
        }
        int g = k >> 4, n = k & 15, c = oct >> 2, q = oct & 3;
        int lane = n + 16 * q;
        bpB[(((size_t)(0 * 8 + bb) * 2 + c) * NGRPC + g) * 64 + lane] = hv;
        bpB[(((size_t)(1 * 8 + bb) * 2 + c) * NGRPC + g) * 64 + lane] = lv;
    } else {
        // ---- A-side pack + per-row inverse norms + flag zeroing ----
        int rg = blockIdx.x - 216;
        int ml = t & 63, s = t >> 6;
        {
            int j0 = rg * 256 + t;          // 36 blocks x 256 = 9216 exactly
            if (br == 0) cfo[b * HW + j0] = 0; else cff[b * HW + j0] = 0;
        }
        int cbase = br ? 28 : 20;
        int m = rg * 64 + ml;
        int pix = (24 + m / 48) * 96 + cbase + (m % 48);
        const float* A = x + (size_t)b * 128 * HW;
        float v[16];
        float part = 0.f;
        #pragma unroll
        for (int e = 0; e < 16; ++e) {
            v[e] = A[(size_t)(s * 16 + e) * HW + pix];
            part += v[e] * v[e];
        }
        red[s][ml] = part;
        __syncthreads();
        if (s == 0) {
            float tot = red[0][ml] + red[1][ml] + red[2][ml] + red[3][ml];
            invA[bb * MROWS + m] = 1.f / sqrtf(tot);
        }
        int rt = ml >> 4;
        size_t fragbase = (((size_t)bb * 36 + rg) * 4 + rt) * 2;
        #pragma unroll
        for (int h = 0; h < 2; ++h) {
            int o = 2 * s + h;                 // global k-octet 0..7
            int c = o >> 2, q = o & 3;
            int lane = (ml & 15) + 16 * q;
            half8 hv, lv;
            #pragma unroll
            for (int e = 0; e < 8; ++e) {
                float a = v[h * 8 + e];
                _Float16 hh = (_Float16)a;
                hv[e] = hh;
                lv[e] = (_Float16)(a - (float)hh);
            }
            apA[((fragbase + c) * 2 + 0) * 64 + lane] = hv;
            apA[((fragbase + c) * 2 + 1) * 64 + lane] = lv;
        }
    }
}

// K1: MFMA masked-argmax over COMPRESSED columns, fp16 split-3, 16x16x32_f16.
// INLINE-ASM PINNED INTERLEAVE: R8/R9/R12/R15 established that the MFMA phase
// (floor 23.6us) and argmax-VALU phase (floor ~19us) SERIALIZE no matter the
// occupancy or source-level pipelining — the compiler emits them as clusters
// and waves convoy. Here the ping-pong phase (group g+1's 24 MFMAs -> accN,
// dependence-free of group g's 16 argmax blocks on accC) is emitted as
// asm volatile in a fixed 3-MFMA : 2-argmax-block super-step pattern (x8).
// asm volatile preserves program order -> one wave issues an MFMA every ~5cyc
// with argmax VALU filling the gaps: ~120 cyc/group vs ~216 serial. MFMAs
// round-robin the 4 acc chains (same-chain ops ~20 issue-cyc apart, covering
// MFMA latency); chain-first MFMA uses C=ZERO via early-clobber.
// 512 blocks (2/CU), bb = blockIdx&7 -> one bb per XCD; block's 4 waves share
// a column-part (R12). Per bb: 252 waves = 36 rg x 7 parts, part p scans
// groups [62p, 62p+62) (last 60); ascending -> exact tie-break.
__global__ __launch_bounds__(256, 2) void argmax_kernel(
    const half8* __restrict__ apA, const half8* __restrict__ bpB,
    float* __restrict__ pval, int* __restrict__ pidx)
{
    int bb = blockIdx.x & 7, lb = blockIdx.x >> 3;     // lb = 0..63 within bb
    int w = threadIdx.x >> 6;                          // wave in block
    int Wl = lb * 4 + w;                               // 0..255 within bb
    if (Wl >= 36 * PARTS) return;                      // 4 idle waves per bb
    int part = Wl / 36, rg = Wl % 36;                  // block's 4 waves: same part
    int gs = part * 62;
    int gc = (part == PARTS - 1) ? 60 : 62;            // even, >= 4
    int lane = threadIdx.x & 63;
    int n = lane & 15;

    // A fragments: ah/al[rt][c]
    half8 ah[4][2], al[4][2];
    {
        size_t base = ((size_t)bb * 36 + rg) * 4;
        #pragma unroll
        for (int rt = 0; rt < 4; ++rt)
            #pragma unroll
            for (int c = 0; c < 2; ++c) {
                ah[rt][c] = apA[(((base + rt) * 2 + c) * 2 + 0) * 64 + lane];
                al[rt][c] = apA[(((base + rt) * 2 + c) * 2 + 1) * 64 + lane];
            }
    }

    float rv[16]; int rix[16];
    #pragma unroll
    for (int r = 0; r < 16; ++r) { rv[r] = -FLT_MAX; rix[r] = 0x7fffffff; }

    const f32x4 ZERO = {};

    // B fragment pointers: idx = (((dt*8+bb)*2 + c)*432 + g)*64 + lane
    const half8* pH0 = bpB + (((size_t)(bb) * 2 + 0) * NGRPC) * 64 + lane;
    const half8* pH1 = bpB + (((size_t)(bb) * 2 + 1) * NGRPC) * 64 + lane;
    const half8* pL0 = bpB + (((size_t)(8 + bb) * 2 + 0) * NGRPC) * 64 + lane;
    const half8* pL1 = bpB + (((size_t)(8 + bb) * 2 + 1) * NGRPC) * 64 + lane;

    half8 buf0[4], buf1[4];
    f32x4 accA[4], accB[4];
    auto ldb = [&](half8* d, int g) {
        d[0] = pH0[(size_t)g * 64];
        d[1] = pH1[(size_t)g * 64];
        d[2] = pL0[(size_t)g * 64];
        d[3] = pL1[(size_t)g * 64];
    };
    // plain (compiler-scheduled) versions for prologue/epilogue groups
    auto mfma_grp = [&](const half8* bf, f32x4* acc) {
        #pragma unroll
        for (int rt = 0; rt < 4; ++rt) {
            acc[rt] = __builtin_amdgcn_mfma_f32_16x16x32_f16(ah[rt][0], bf[0], ZERO, 0, 0, 0);
            acc[rt] = __builtin_amdgcn_mfma_f32_16x16x32_f16(al[rt][0], bf[0], acc[rt], 0, 0, 0);
            acc[rt] = __builtin_amdgcn_mfma_f32_16x16x32_f16(ah[rt][0], bf[2], acc[rt], 0, 0, 0);
            acc[rt] = __builtin_amdgcn_mfma_f32_16x16x32_f16(ah[rt][1], bf[1], acc[rt], 0, 0, 0);
            acc[rt] = __builtin_amdgcn_mfma_f32_16x16x32_f16(al[rt][1], bf[1], acc[rt], 0, 0, 0);
            acc[rt] = __builtin_amdgcn_mfma_f32_16x16x32_f16(ah[rt][1], bf[3], acc[rt], 0, 0, 0);
        }
    };
    auto argmax_grp = [&](const f32x4* acc, int g) {
        int j = g * 16 + n;
        #pragma unroll
        for (int rt = 0; rt < 4; ++rt)
            #pragma unroll
            for (int r = 0; r < 4; ++r) {
                float s = acc[rt][r];
                int slot = rt * 4 + r;
                if (s > rv[slot]) { rv[slot] = s; rix[slot] = j; }
            }
    };
    // pinned phase: 24 MFMAs (accN <- bf, group g+1) interleaved with 16
    // argmax blocks (accC, group gC) as 8 super-steps of {3 MFMA, 2 argmax}.
    auto phase = [&](const half8* bf, f32x4* accN, const f32x4* accC, int gC) {
        int j = gC * 16 + n;
        #pragma unroll
        for (int ss = 0; ss < 8; ++ss) {
            #pragma unroll
            for (int mi = 0; mi < 3; ++mi) {
                int m = ss * 3 + mi;
                int rt = m & 3, step = m >> 2;
                if (step == 0) {
                    asm volatile("v_mfma_f32_16x16x32_f16 %0, %1, %2, %3"
                                 : "=&v"(accN[rt])
                                 : "v"(ah[rt][0]), "v"(bf[0]), "v"(ZERO));
                } else {
                    const half8& A = (step == 1) ? al[rt][0] :
                                     (step == 2) ? ah[rt][0] :
                                     (step == 3) ? ah[rt][1] :
                                     (step == 4) ? al[rt][1] : ah[rt][1];
                    const half8& B = (step == 1) ? bf[0] :
                                     (step == 2) ? bf[2] :
                                     (step == 3) ? bf[1] :
                                     (step == 4) ? bf[1] : bf[3];
                    asm volatile("v_mfma_f32_16x16x32_f16 %0, %1, %2, %0"
                                 : "+v"(accN[rt]) : "v"(A), "v"(B));
                }
            }
            #pragma unroll
            for (int ai = 0; ai < 2; ++ai) {
                int slot = ss * 2 + ai;
                int rt = slot >> 2, r = slot & 3;
                float s = accC[rt][r];
                asm volatile("v_cmp_gt_f32 vcc, %2, %0\n\t"
                             "v_cndmask_b32 %0, %0, %2, vcc\n\t"
                             "v_cndmask_b32 %1, %1, %3, vcc"
                             : "+v"(rv[slot]), "+v"(rix[slot])
                             : "v"(s), "v"(j) : "vcc");
            }
        }
    };

    ldb(buf0, gs);
    ldb(buf1, gs + 1);
    mfma_grp(buf0, accA);                  // group gs (prologue, no overlap)
    #pragma unroll 1
    for (int k2 = 0; k2 < (gc - 2) / 2; ++k2) {
        int g0 = gs + 2 * k2;
        ldb(buf0, g0 + 2);                 // prefetch next even group
        phase(buf1, accB, accA, g0);       // MFMAs(g0+1) || argmax(g0)
        ldb(buf1, g0 + 3);                 // prefetch next odd group (<= gs+gc-1)
        phase(buf0, accA, accB, g0 + 1);   // MFMAs(g0+2) || argmax(g0+1)
    }
    phase(buf1, accB, accA, gs + gc - 2);  // MFMAs(gs+gc-1) || argmax(gs+gc-2)
    argmax_grp(accB, gs + gc - 1);         // epilogue

    // cross-lane argmax over the 16 columns within each 16-lane segment
    #pragma unroll
    for (int slot = 0; slot < 16; ++slot) {
        float v = rv[slot]; int ix = rix[slot];
        #pragma unroll
        for (int off = 1; off <= 8; off <<= 1) {
            float ov = __shfl_xor(v, off, 16);
            int   oi = __shfl_xor(ix, off, 16);
            if (ov > v || (ov == v && oi < ix)) { v = ov; ix = oi; }
        }
        if (n == 0) {
            int q = lane >> 4;               // quad: rows quad*4+reg
            int rt = slot >> 2, r = slot & 3;
            int mm = rg * 64 + rt * 16 + q * 4 + r;
            pval[((size_t)bb * PARTS + part) * MROWS + mm] = v;
            pidx[((size_t)bb * PARTS + part) * MROWS + mm] = ix;
        }
    }
}

// K2: merge 7 parts per (bb,m), apply precomputed 1/|a|, ori flag, scatter col
// flags (converting compressed index -> original j; map is monotonic so the
// compressed tie-break equals the original-index tie-break).
__global__ __launch_bounds__(256) void merge_kernel(
    const float* __restrict__ pval, const int* __restrict__ pidx,
    const float* __restrict__ invA, int* __restrict__ ori,
    int* __restrict__ cfo, int* __restrict__ cff)
{
    int gid = blockIdx.x * 256 + threadIdx.x;      // 36 blocks -> 9216 = 4*2304
    int b = gid / MROWS, m = gid % MROWS;
    float bv[2]; int bi[2];
    #pragma unroll
    for (int br = 0; br < 2; ++br) {
        int bb = b * 2 + br;
        float v = -FLT_MAX; int id = 0x7fffffff;
        #pragma unroll
        for (int s = 0; s < PARTS; ++s) {
            float pv = pval[((size_t)bb * PARTS + s) * MROWS + m];
            int   pi = pidx[((size_t)bb * PARTS + s) * MROWS + m];
            if (pv > v || (pv == v && pi < id)) { v = pv; id = pi; }
        }
        bv[br] = v * invA[bb * MROWS + m];
        bi[br] = comp_to_orig(id, br ? 28 : 20);
    }
    bool o = bv[0] >= bv[1];
    ori[gid] = o ? 1 : 0;
    cfo[b * HW + bi[0]] = 1;
    cff[b * HW + bi[1]] = 1;
}

// K3: S[c] = sum over flagged columns j of Bm[c][j]. One block per (bb, c).
__global__ __launch_bounds__(256) void ssum_kernel(
    const float* __restrict__ x, const float* __restrict__ flip,
    const int* __restrict__ cfo, const int* __restrict__ cff,
    float* __restrict__ So, float* __restrict__ Sf)
{
    int blk = blockIdx.x;                  // 8 = b*2+br
    int c   = blockIdx.y;                  // 64 channels
    int b = blk >> 1, br = blk & 1;
    const float* Bm = br ? (flip + (size_t)b * 64 * HW)
                         : (x + (size_t)b * 128 * HW + (size_t)64 * HW);
    const int* cf = (br ? cff : cfo) + (size_t)b * HW;
    float* S = (br ? Sf : So) + b * 64;

    const float* row = Bm + (size_t)c * HW;
    float acc = 0.f;
    for (int j = threadIdx.x; j < HW; j += 256) {
        if (cf[j]) acc += row[j];
    }
    for (int off = 32; off > 0; off >>= 1) acc += __shfl_down(acc, off, 64);
    __shared__ float part[4];
    int lane = threadIdx.x & 63, w = threadIdx.x >> 6;
    if (lane == 0) part[w] = acc;
    __syncthreads();
    if (threadIdx.x == 0) S[c] = part[0] + part[1] + part[2] + part[3];
}

// K4: assemble output [4][192][9216]
__global__ __launch_bounds__(256) void assemble_kernel(
    const float* __restrict__ x, const int* __restrict__ ori,
    const float* __restrict__ So, const float* __restrict__ Sf,
    float* __restrict__ out)
{
    int idx = blockIdx.x * 256 + threadIdx.x;      // float4 index; grid covers exactly
    const int PER_B4 = 192 * (HW / 4);             // 442368
    int b = idx / PER_B4;
    int rem = idx - b * PER_B4;
    int ch = rem / (HW / 4);
    int p4 = rem % (HW / 4);
    float4 v;
    if (ch < 128) {
        v = reinterpret_cast<const float4*>(x + ((size_t)b * 128 + ch) * HW)[p4];
    } else {
        int c = ch - 128;
        int pix = p4 * 4;
        int r = pix / 96, cc = pix % 96;           // 4 consecutive pixels share the row (96%4==0)
        float so = So[b * 64 + c], sf = Sf[b * 64 + c];
        float vals[4];
        #pragma unroll
        for (int i = 0; i < 4; ++i) {
            int ccc = cc + i;
            if (r >= 24 && r < 72 && ccc >= 20 && ccc < 68) {
                int mm = (r - 24) * 48 + (ccc - 20);
                vals[i] = ori[b * MROWS + mm] ? so : sf;
            } else vals[i] = 0.f;
        }
        v = make_float4(vals[0], vals[1], vals[2], vals[3]);
    }
    reinterpret_cast<float4*>(out)[idx] = v;
}

extern "C" void kernel_launch(void* const* d_in, const int* in_sizes, int n_in,
                              void* d_out, int out_size, void* d_ws, size_t ws_size,
                              hipStream_t stream) {
    const float* x    = (const float*)d_in[0];   // [4,128,9216]
    const float* flip = (const float*)d_in[1];   // [4,64,9216]
    char* w = (char*)d_ws;
    half8* bpB  = (half8*)(w + OFF_BPB);
    half8* apA  = (half8*)(w + OFF_APA);
    float* pval = (float*)(w + OFF_PVAL);
    int*   pidx = (int*)  (w + OFF_PIDX);
    int*   ori  = (int*)  (w + OFF_ORI);
    int*   cfo  = (int*)  (w + OFF_CFO);
    int*   cff  = (int*)  (w + OFF_CFF);
    float* So   = (float*)(w + OFF_SO);
    float* Sf   = (float*)(w + OFF_SF);
    float* invA = (float*)(w + OFF_INVA);
    float* out  = (float*)d_out;

    pack_kernel<<<dim3(252, 8), 256, 0, stream>>>(x, flip, bpB, apA, invA, cfo, cff);
    argmax_kernel<<<512, 256, 0, stream>>>(apA, bpB, pval, pidx);
    merge_kernel<<<36, 256, 0, stream>>>(pval, pidx, invA, ori, cfo, cff);
    ssum_kernel<<<dim3(8, 64), 256, 0, stream>>>(x, flip, cfo, cff, So, Sf);
    assemble_kernel<<<6912, 256, 0, stream>>>(x, ori, So, Sf, out);
}

// Round 17
// 152.184 us; speedup vs baseline: 1.1279x; 1.1279x over previous
//
#include <hip/hip_runtime.h>
#include <cfloat>
#include <cstddef>
#include <cstdint>

#define HW 9216
#define MROWS 2304
#define PARTS 7         // column-parts per (bb,row-group): 62|60 16-col groups each
#define NGRPC 432       // 6912/16 compressed groups (valid columns only)

typedef _Float16 half8 __attribute__((ext_vector_type(8)));
typedef float f32x4 __attribute__((ext_vector_type(4)));

// Compressed column space: only the 6912 non-hole columns, ascending original j.
//   k < 2304            -> j = k                       (rows 0..23)
//   2304 <= k < 4608    -> r = 24 + (k-2304)/48, c = (k-2304)%48,
//                          j = r*96 + (c < cb ? c : c+48)   (cb = 20 or 28 per branch)
//   k >= 4608           -> j = k + 2304                (rows 72..95)
// Mapping is strictly increasing -> compressed-index tie-break == original tie-break.
// bpack (B fragments, 16x16x32 layout): half8 index = (((dt*8+bb)*2 + c)*432 + g)*64 + lane
// apack (A fragments): half8 index = ((((bb*36+rg)*4 + rt)*2 + c)*2 + dt)*64 + lane
constexpr size_t OFF_BPB  = 0;                                 // 14,155,776 B
constexpr size_t OFF_APA  = OFF_BPB + 2ull*8*2*NGRPC*64*16;
constexpr size_t OFF_PVAL = OFF_APA + 8ull*36*4*2*2*64*16;     // +4,718,592
constexpr size_t OFF_PIDX = OFF_PVAL + 8ull*PARTS*MROWS*4;     // 516,096 each
constexpr size_t OFF_ORI  = OFF_PIDX + 8ull*PARTS*MROWS*4;
constexpr size_t OFF_CFO  = OFF_ORI  + 36864;
constexpr size_t OFF_CFF  = OFF_CFO  + 147456;
constexpr size_t OFF_SO   = OFF_CFF  + 147456;
constexpr size_t OFF_SF   = OFF_SO   + 1024;
constexpr size_t OFF_INVA = OFF_SF   + 1024;                   // 8*2304 f32

__device__ __forceinline__ int comp_to_orig(int k, int cb) {
    if (k < 2304) return k;
    if (k < 4608) {
        int k2 = k - 2304;
        int r = 24 + k2 / 48, c = k2 % 48;
        return r * 96 + (c < cb ? c : c + 48);
    }
    return k + 2304;
}

// K0: fused pack (bodies identical to the validated split kernels).
// grid (252, 8 bb), 256t.
//   blockIdx.x < 216 : B-side pack over compressed cols (k = x*32 + t&31, oct = t>>5)
//   blockIdx.x >= 216: A-side pack + inv norms + flag zeroing, rg = x-216
__global__ __launch_bounds__(256) void pack_kernel(
    const float* __restrict__ x, const float* __restrict__ flip,
    half8* __restrict__ bpB, half8* __restrict__ apA, float* __restrict__ invA,
    int* __restrict__ cfo, int* __restrict__ cff)
{
    __shared__ float nsq[8][32];
    __shared__ float ivs[32];
    __shared__ float red[4][64];
    int bb = blockIdx.y, b = bb >> 1, br = bb & 1;
    int t = threadIdx.x;
    if (blockIdx.x < 216) {
        // ---- B-side pack ----
        int col = t & 31, oct = t >> 5;
        int k = blockIdx.x * 32 + col;
        int cb = br ? 28 : 20;
        int j = comp_to_orig(k, cb);
        const float* Bm = br ? (flip + (size_t)b * 64 * HW)
                             : (x + (size_t)b * 128 * HW + (size_t)64 * HW);
        float v[8];
        float part = 0.f;
        #pragma unroll
        for (int e = 0; e < 8; ++e) {
            v[e] = Bm[(size_t)(oct * 8 + e) * HW + j];
            part += v[e] * v[e];
        }
        nsq[oct][col] = part;
        __syncthreads();
        if (oct == 0) {
            float tot = 0.f;
            #pragma unroll
            for (int o = 0; o < 8; ++o) tot += nsq[o][col];
            ivs[col] = 1.f / sqrtf(tot);
        }
        __syncthreads();
        float iv = ivs[col];
        half8 hv, lv;
        #pragma unroll
        for (int e = 0; e < 8; ++e) {
            float s = v[e] * iv;
            _Float16 h = (_Float16)s;
            hv[e] = h;
            lv[e] = (_Float16)(s - (float)h);
        }
        int g = k >> 4, n = k & 15, c = oct >> 2, q = oct & 3;
        int lane = n + 16 * q;
        bpB[(((size_t)(0 * 8 + bb) * 2 + c) * NGRPC + g) * 64 + lane] = hv;
        bpB[(((size_t)(1 * 8 + bb) * 2 + c) * NGRPC + g) * 64 + lane] = lv;
    } else {
        // ---- A-side pack + per-row inverse norms + flag zeroing ----
        int rg = blockIdx.x - 216;
        int ml = t & 63, s = t >> 6;
        {
            int j0 = rg * 256 + t;          // 36 blocks x 256 = 9216 exactly
            if (br == 0) cfo[b * HW + j0] = 0; else cff[b * HW + j0] = 0;
        }
        int cbase = br ? 28 : 20;
        int m = rg * 64 + ml;
        int pix = (24 + m / 48) * 96 + cbase + (m % 48);
        const float* A = x + (size_t)b * 128 * HW;
        float v[16];
        float part = 0.f;
        #pragma unroll
        for (int e = 0; e < 16; ++e) {
            v[e] = A[(size_t)(s * 16 + e) * HW + pix];
            part += v[e] * v[e];
        }
        red[s][ml] = part;
        __syncthreads();
        if (s == 0) {
            float tot = red[0][ml] + red[1][ml] + red[2][ml] + red[3][ml];
            invA[bb * MROWS + m] = 1.f / sqrtf(tot);
        }
        int rt = ml >> 4;
        size_t fragbase = (((size_t)bb * 36 + rg) * 4 + rt) * 2;
        #pragma unroll
        for (int h = 0; h < 2; ++h) {
            int o = 2 * s + h;                 // global k-octet 0..7
            int c = o >> 2, q = o & 3;
            int lane = (ml & 15) + 16 * q;
            half8 hv, lv;
            #pragma unroll
            for (int e = 0; e < 8; ++e) {
                float a = v[h * 8 + e];
                _Float16 hh = (_Float16)a;
                hv[e] = hh;
                lv[e] = (_Float16)(a - (float)hh);
            }
            apA[((fragbase + c) * 2 + 0) * 64 + lane] = hv;
            apA[((fragbase + c) * 2 + 1) * 64 + lane] = lv;
        }
    }
}

// K1: MFMA masked-argmax over COMPRESSED columns, fp16 split-3, 16x16x32_f16.
// EXACT R12 body (best measured: 46.8us). Structural plateau established by
// R8/R9/R12/R15/R16: MFMA and argmax-VALU execute on the same SIMD datapath
// — occupancy, anti-phasing, compiler pipelining, and asm-pinned interleave
// are all null. Time = MFMA-cycles (~24us floor) + VALU-cycles (~12us) +
// issue/latency. 512 blocks (2/CU), bb = blockIdx&7 -> one bb per XCD;
// block's 4 waves share a column-part (R12, +1.4us via L1 temporal hits).
// Per bb: 252 waves = 36 rg x 7 parts, part p scans groups [62p, 62p+62)
// (last 60); ascending -> exact tie-break.
__global__ __launch_bounds__(256, 2) void argmax_kernel(
    const half8* __restrict__ apA, const half8* __restrict__ bpB,
    float* __restrict__ pval, int* __restrict__ pidx)
{
    int bb = blockIdx.x & 7, lb = blockIdx.x >> 3;     // lb = 0..63 within bb
    int w = threadIdx.x >> 6;                          // wave in block
    int Wl = lb * 4 + w;                               // 0..255 within bb
    if (Wl >= 36 * PARTS) return;                      // 4 idle waves per bb
    int part = Wl / 36, rg = Wl % 36;                  // block's 4 waves: same part
    int gs = part * 62;
    int gc = (part == PARTS - 1) ? 60 : 62;            // even, >= 2
    int lane = threadIdx.x & 63;
    int n = lane & 15;

    // A fragments: ah/al[rt][c]
    half8 ah[4][2], al[4][2];
    {
        size_t base = ((size_t)bb * 36 + rg) * 4;
        #pragma unroll
        for (int rt = 0; rt < 4; ++rt)
            #pragma unroll
            for (int c = 0; c < 2; ++c) {
                ah[rt][c] = apA[(((base + rt) * 2 + c) * 2 + 0) * 64 + lane];
                al[rt][c] = apA[(((base + rt) * 2 + c) * 2 + 1) * 64 + lane];
            }
    }

    float rv[16]; int rix[16];
    #pragma unroll
    for (int r = 0; r < 16; ++r) { rv[r] = -FLT_MAX; rix[r] = 0x7fffffff; }

    const f32x4 ZERO = {};

    // B fragment pointers: idx = (((dt*8+bb)*2 + c)*432 + g)*64 + lane
    const half8* pH0 = bpB + (((size_t)(bb) * 2 + 0) * NGRPC) * 64 + lane;
    const half8* pH1 = bpB + (((size_t)(bb) * 2 + 1) * NGRPC) * 64 + lane;
    const half8* pL0 = bpB + (((size_t)(8 + bb) * 2 + 0) * NGRPC) * 64 + lane;
    const half8* pL1 = bpB + (((size_t)(8 + bb) * 2 + 1) * NGRPC) * 64 + lane;

    half8 buf0[4], buf1[4];
    auto ldb = [&](half8* d, int g) {
        d[0] = pH0[(size_t)g * 64];
        d[1] = pH1[(size_t)g * 64];
        d[2] = pL0[(size_t)g * 64];
        d[3] = pL1[(size_t)g * 64];
    };
    auto compute = [&](const half8* bf, int g) {       // g = absolute group index
        f32x4 acc[4];
        __builtin_amdgcn_s_setprio(1);
        #pragma unroll
        for (int rt = 0; rt < 4; ++rt) {
            acc[rt] = __builtin_amdgcn_mfma_f32_16x16x32_f16(ah[rt][0], bf[0], ZERO, 0, 0, 0);
            acc[rt] = __builtin_amdgcn_mfma_f32_16x16x32_f16(al[rt][0], bf[0], acc[rt], 0, 0, 0);
            acc[rt] = __builtin_amdgcn_mfma_f32_16x16x32_f16(ah[rt][0], bf[2], acc[rt], 0, 0, 0);
            acc[rt] = __builtin_amdgcn_mfma_f32_16x16x32_f16(ah[rt][1], bf[1], acc[rt], 0, 0, 0);
            acc[rt] = __builtin_amdgcn_mfma_f32_16x16x32_f16(al[rt][1], bf[1], acc[rt], 0, 0, 0);
            acc[rt] = __builtin_amdgcn_mfma_f32_16x16x32_f16(ah[rt][1], bf[3], acc[rt], 0, 0, 0);
        }
        __builtin_amdgcn_s_setprio(0);
        int j = g * 16 + n;           // this lane's COMPRESSED column
        #pragma unroll
        for (int rt = 0; rt < 4; ++rt)
            #pragma unroll
            for (int r = 0; r < 4; ++r) {
                float s = acc[rt][r];
                int slot = rt * 4 + r;
                if (s > rv[slot]) { rv[slot] = s; rix[slot] = j; }
            }
    };

    ldb(buf0, gs);
    #pragma unroll 1
    for (int gi = 0; gi < gc - 2; gi += 2) {
        ldb(buf1, gs + gi + 1);
        compute(buf0, gs + gi);
        ldb(buf0, gs + gi + 2);
        compute(buf1, gs + gi + 1);
    }
    ldb(buf1, gs + gc - 1);
    compute(buf0, gs + gc - 2);
    compute(buf1, gs + gc - 1);

    // cross-lane argmax over the 16 columns within each 16-lane segment
    #pragma unroll
    for (int slot = 0; slot < 16; ++slot) {
        float v = rv[slot]; int ix = rix[slot];
        #pragma unroll
        for (int off = 1; off <= 8; off <<= 1) {
            float ov = __shfl_xor(v, off, 16);
            int   oi = __shfl_xor(ix, off, 16);
            if (ov > v || (ov == v && oi < ix)) { v = ov; ix = oi; }
        }
        if (n == 0) {
            int q = lane >> 4;               // quad: rows quad*4+reg
            int rt = slot >> 2, r = slot & 3;
            int mm = rg * 64 + rt * 16 + q * 4 + r;
            pval[((size_t)bb * PARTS + part) * MROWS + mm] = v;
            pidx[((size_t)bb * PARTS + part) * MROWS + mm] = ix;
        }
    }
}

// K2: merge 7 parts per (bb,m), apply precomputed 1/|a|, ori flag, scatter col
// flags (converting compressed index -> original j; map is monotonic so the
// compressed tie-break equals the original-index tie-break).
__global__ __launch_bounds__(256) void merge_kernel(
    const float* __restrict__ pval, const int* __restrict__ pidx,
    const float* __restrict__ invA, int* __restrict__ ori,
    int* __restrict__ cfo, int* __restrict__ cff)
{
    int gid = blockIdx.x * 256 + threadIdx.x;      // 36 blocks -> 9216 = 4*2304
    int b = gid / MROWS, m = gid % MROWS;
    float bv[2]; int bi[2];
    #pragma unroll
    for (int br = 0; br < 2; ++br) {
        int bb = b * 2 + br;
        float v = -FLT_MAX; int id = 0x7fffffff;
        #pragma unroll
        for (int s = 0; s < PARTS; ++s) {
            float pv = pval[((size_t)bb * PARTS + s) * MROWS + m];
            int   pi = pidx[((size_t)bb * PARTS + s) * MROWS + m];
            if (pv > v || (pv == v && pi < id)) { v = pv; id = pi; }
        }
        bv[br] = v * invA[bb * MROWS + m];
        bi[br] = comp_to_orig(id, br ? 28 : 20);
    }
    bool o = bv[0] >= bv[1];
    ori[gid] = o ? 1 : 0;
    cfo[b * HW + bi[0]] = 1;
    cff[b * HW + bi[1]] = 1;
}

// K3: S[c] = sum over flagged columns j of Bm[c][j]. One block per (bb, c).
// Branchless + vectorized: float4 row loads, int4 flag loads, fmaf by flag
// (replaces the divergent per-element branch + 36 scalar iterations with 9
// vector iterations; flags are 0/1 so multiply is exact).
__global__ __launch_bounds__(256) void ssum_kernel(
    const float* __restrict__ x, const float* __restrict__ flip,
    const int* __restrict__ cfo, const int* __restrict__ cff,
    float* __restrict__ So, float* __restrict__ Sf)
{
    int blk = blockIdx.x;                  // 8 = b*2+br
    int c   = blockIdx.y;                  // 64 channels
    int b = blk >> 1, br = blk & 1;
    const float* Bm = br ? (flip + (size_t)b * 64 * HW)
                         : (x + (size_t)b * 128 * HW + (size_t)64 * HW);
    const int* cf = (br ? cff : cfo) + (size_t)b * HW;
    float* S = (br ? Sf : So) + b * 64;

    const float4* row4 = reinterpret_cast<const float4*>(Bm + (size_t)c * HW);
    const int4*   cf4  = reinterpret_cast<const int4*>(cf);
    float acc = 0.f;
    #pragma unroll
    for (int it = 0; it < 9; ++it) {               // 9*256 = 2304 = HW/4 exactly
        int j4 = it * 256 + threadIdx.x;
        float4 v = row4[j4];
        int4   f = cf4[j4];
        acc = fmaf(v.x, (float)f.x, acc);
        acc = fmaf(v.y, (float)f.y, acc);
        acc = fmaf(v.z, (float)f.z, acc);
        acc = fmaf(v.w, (float)f.w, acc);
    }
    for (int off = 32; off > 0; off >>= 1) acc += __shfl_down(acc, off, 64);
    __shared__ float part[4];
    int lane = threadIdx.x & 63, w = threadIdx.x >> 6;
    if (lane == 0) part[w] = acc;
    __syncthreads();
    if (threadIdx.x == 0) S[c] = part[0] + part[1] + part[2] + part[3];
}

// K4: assemble output [4][192][9216]
__global__ __launch_bounds__(256) void assemble_kernel(
    const float* __restrict__ x, const int* __restrict__ ori,
    const float* __restrict__ So, const float* __restrict__ Sf,
    float* __restrict__ out)
{
    int idx = blockIdx.x * 256 + threadIdx.x;      // float4 index; grid covers exactly
    const int PER_B4 = 192 * (HW / 4);             // 442368
    int b = idx / PER_B4;
    int rem = idx - b * PER_B4;
    int ch = rem / (HW / 4);
    int p4 = rem % (HW / 4);
    float4 v;
    if (ch < 128) {
        v = reinterpret_cast<const float4*>(x + ((size_t)b * 128 + ch) * HW)[p4];
    } else {
        int c = ch - 128;
        int pix = p4 * 4;
        int r = pix / 96, cc = pix % 96;           // 4 consecutive pixels share the row (96%4==0)
        float so = So[b * 64 + c], sf = Sf[b * 64 + c];
        float vals[4];
        #pragma unroll
        for (int i = 0; i < 4; ++i) {
            int ccc = cc + i;
            if (r >= 24 && r < 72 && ccc >= 20 && ccc < 68) {
                int mm = (r - 24) * 48 + (ccc - 20);
                vals[i] = ori[b * MROWS + mm] ? so : sf;
            } else vals[i] = 0.f;
        }
        v = make_float4(vals[0], vals[1], vals[2], vals[3]);
    }
    reinterpret_cast<float4*>(out)[idx] = v;
}

extern "C" void kernel_launch(void* const* d_in, const int* in_sizes, int n_in,
                              void* d_out, int out_size, void* d_ws, size_t ws_size,
                              hipStream_t stream) {
    const float* x    = (const float*)d_in[0];   // [4,128,9216]
    const float* flip = (const float*)d_in[1];   // [4,64,9216]
    char* w = (char*)d_ws;
    half8* bpB  = (half8*)(w + OFF_BPB);
    half8* apA  = (half8*)(w + OFF_APA);
    float* pval = (float*)(w + OFF_PVAL);
    int*   pidx = (int*)  (w + OFF_PIDX);
    int*   ori  = (int*)  (w + OFF_ORI);
    int*   cfo  = (int*)  (w + OFF_CFO);
    int*   cff  = (int*)  (w + OFF_CFF);
    float* So   = (float*)(w + OFF_SO);
    float* Sf   = (float*)(w + OFF_SF);
    float* invA = (float*)(w + OFF_INVA);
    float* out  = (float*)d_out;

    pack_kernel<<<dim3(252, 8), 256, 0, stream>>>(x, flip, bpB, apA, invA, cfo, cff);
    argmax_kernel<<<512, 256, 0, stream>>>(apA, bpB, pval, pidx);
    merge_kernel<<<36, 256, 0, stream>>>(pval, pidx, invA, ori, cfo, cff);
    ssum_kernel<<<dim3(8, 64), 256, 0, stream>>>(x, flip, cfo, cff, So, Sf);
    assemble_kernel<<<6912, 256, 0, stream>>>(x, ori, So, Sf, out);
}